// Round 7
// baseline (171.550 us; speedup 1.0000x reference)
//
#include <hip/hip_runtime.h>
#include <hip/hip_bf16.h>
#include <cstdint>
#include <cstddef>

#define NN 8192
#define FIN 256
#define FO 128
#define SPLITK 8
#define JCH 1024   // NN / SPLITK
#define NIT 16     // JCH / 64

typedef float f32x4 __attribute__((ext_vector_type(4)));
typedef _Float16 f16x8 __attribute__((ext_vector_type(8)));

typedef __attribute__((address_space(3))) void lds_void;
typedef const __attribute__((address_space(1))) void glb_void;
__device__ __forceinline__ void gl_lds16(const void* g, void* l) {
  __builtin_amdgcn_global_load_lds((glb_void*)g, (lds_void*)l, 16, 0, 0);
}

__device__ __forceinline__ unsigned enc_f32(float f) {
  unsigned u = __float_as_uint(f);
  return (u & 0x80000000u) ? ~u : (u | 0x80000000u);
}
__device__ __forceinline__ float dec_f32(unsigned u) {
  unsigned b = (u & 0x80000000u) ? (u ^ 0x80000000u) : ~u;
  return __uint_as_float(b);
}

// ---------------- K1: h = x @ W  (8192x256 @ 256x128) ----------------
__global__ void k1_xw(const float* __restrict__ x, const float* __restrict__ W,
                      float* __restrict__ h, unsigned* __restrict__ enc) {
  __shared__ float xs[32 * 66];
  __shared__ float Ws[64 * 128];
  int t = threadIdx.x;
  int r0 = blockIdx.x * 32;
  if (blockIdx.x == 0 && t == 0) *enc = 0u;  // init for K2's atomicMax
  int r = t & 31, cg = t >> 5;
  float acc[16];
#pragma unroll
  for (int i = 0; i < 16; ++i) acc[i] = 0.f;
  for (int ko = 0; ko < 4; ++ko) {
    __syncthreads();
    {
      int rr = t >> 3, kc = (t & 7) * 8;
      const float2* src = (const float2*)(x + (size_t)(r0 + rr) * FIN + ko * 64 + kc);
      float2* dst = (float2*)&xs[rr * 66 + kc];
#pragma unroll
      for (int q = 0; q < 4; ++q) dst[q] = src[q];
    }
    {
      int kk = t >> 2, q = t & 3;
      const float4* src = (const float4*)(W + (size_t)(ko * 64 + kk) * FO + q * 32);
      float4* dst = (float4*)&Ws[kk * 128 + q * 32];
#pragma unroll
      for (int i = 0; i < 8; ++i) dst[i] = src[i];
    }
    __syncthreads();
#pragma unroll 8
    for (int kk = 0; kk < 64; ++kk) {
      float xv = xs[r * 66 + kk];
      const float4* wr = (const float4*)&Ws[kk * 128 + cg * 16];
      float4 w0 = wr[0], w1 = wr[1], w2 = wr[2], w3 = wr[3];
      acc[0]  = fmaf(xv, w0.x, acc[0]);  acc[1]  = fmaf(xv, w0.y, acc[1]);
      acc[2]  = fmaf(xv, w0.z, acc[2]);  acc[3]  = fmaf(xv, w0.w, acc[3]);
      acc[4]  = fmaf(xv, w1.x, acc[4]);  acc[5]  = fmaf(xv, w1.y, acc[5]);
      acc[6]  = fmaf(xv, w1.z, acc[6]);  acc[7]  = fmaf(xv, w1.w, acc[7]);
      acc[8]  = fmaf(xv, w2.x, acc[8]);  acc[9]  = fmaf(xv, w2.y, acc[9]);
      acc[10] = fmaf(xv, w2.z, acc[10]); acc[11] = fmaf(xv, w2.w, acc[11]);
      acc[12] = fmaf(xv, w3.x, acc[12]); acc[13] = fmaf(xv, w3.y, acc[13]);
      acc[14] = fmaf(xv, w3.z, acc[14]); acc[15] = fmaf(xv, w3.w, acc[15]);
    }
  }
  float* hp = h + (size_t)(r0 + r) * FO + cg * 16;
#pragma unroll
  for (int i = 0; i < 4; ++i)
    ((float4*)hp)[i] = make_float4(acc[4 * i], acc[4 * i + 1], acc[4 * i + 2], acc[4 * i + 3]);
}

// ---------------- K2: hT (fp16 transpose), s1, s2, max(s2) ----------------
__global__ void k2_prep(const float* __restrict__ h, const float* __restrict__ a,
                        _Float16* __restrict__ hT,
                        float* __restrict__ s1, float* __restrict__ s2,
                        unsigned* __restrict__ enc) {
  __shared__ float ht[64 * 129];
  int t = threadIdx.x;
  int r0 = blockIdx.x * 64;
  {
    int rr = t >> 2, q = t & 3;
    const float4* src = (const float4*)(h + (size_t)(r0 + rr) * FO + q * 32);
    float* dst = &ht[rr * 129 + q * 32];
#pragma unroll
    for (int i = 0; i < 8; ++i) {
      float4 v = src[i];
      dst[4 * i + 0] = v.x; dst[4 * i + 1] = v.y;
      dst[4 * i + 2] = v.z; dst[4 * i + 3] = v.w;
    }
  }
  __syncthreads();
  {
    int c = t >> 1, half = t & 1;
    alignas(16) _Float16 buf[32];
#pragma unroll
    for (int i = 0; i < 32; ++i) buf[i] = (_Float16)ht[(half * 32 + i) * 129 + c];
    int4* d = (int4*)(hT + (size_t)c * NN + r0 + half * 32);
#pragma unroll
    for (int i = 0; i < 4; ++i) d[i] = ((const int4*)buf)[i];
  }
  if (t < 64) {
    int row = r0 + t;
    float v1 = 0.f, v2 = 0.f;
#pragma unroll 16
    for (int c = 0; c < FO; ++c) {
      float hv = ht[t * 129 + c];
      v1 = fmaf(hv, a[c], v1);
      v2 = fmaf(hv, a[FO + c], v2);
    }
    s1[row] = v1; s2[row] = v2;
    float m = v2;
#pragma unroll
    for (int off = 1; off < 64; off <<= 1) m = fmaxf(m, __shfl_xor(m, off));
    if (t == 0) atomicMax(enc, enc_f32(m));
  }
}

// weight: w = bit ? exp(leaky(s1+s2) - m) : 0, rounded to fp16;
// den accumulates the *rounded* weight in f32 for exact normalization consistency.
__device__ __forceinline__ _Float16 wel(unsigned av, float s2v, float s1v, float mv, float& sum) {
  float tt = s1v + s2v;
  tt = fmaxf(tt, 0.01f * tt);  // leaky_relu
  float wf = av ? __expf(tt - mv) : 0.f;
  _Float16 wh = (_Float16)wf;
  sum += (float)wh;
  return wh;
}

#define LOADSET(S, J)                                                            \
  _Pragma("unroll")                                                              \
  for (int rr = 0; rr < 16; ++rr) S[rr] = abase[(size_t)rr * NN + (J)];

// One j-step of 64 cols. CUR consumed this body (drained by PREVIOUS body's
// end-wait -> no wait at the ballot). LD <- adj for body TI+2 (distance-2).
// End-of-body vmcnt(16) drains adj(TI+1) (2 bodies old) + stage(TI+1).
#define K4BODY(CUR, LD, TI, DOLOAD, ENDW)                                        \
  {                                                                              \
    stage(buf ^ 1, jbeg + ((TI) + 1) * 64);                                      \
    if (DOLOAD) { LOADSET(LD, jbeg + ((TI) + 2) * 64) }                          \
    __builtin_amdgcn_sched_barrier(0);                                           \
    K4COMPUTE(CUR, TI)                                                           \
    __builtin_amdgcn_sched_barrier(0);                                           \
    asm volatile("s_waitcnt vmcnt(" #ENDW ")" ::: "memory");                     \
    __builtin_amdgcn_s_barrier();                                                \
    __builtin_amdgcn_sched_barrier(0);                                           \
    buf ^= 1;                                                                    \
  }

#define K4LAST(CUR, TI)                                                          \
  {                                                                              \
    K4COMPUTE(CUR, TI)                                                           \
  }

#define K4COMPUTE(CR, TI)                                                        \
  {                                                                              \
    unsigned mlo = 0u, mhi = 0u;                                                 \
    _Pragma("unroll")                                                            \
    for (int rr = 0; rr < 16; ++rr) {                                            \
      unsigned long long br = __ballot(CR[rr] > 0);                              \
      bool sel = (l15 == rr);                                                    \
      mlo = sel ? (unsigned)br : mlo;                                            \
      mhi = sel ? (unsigned)(br >> 32) : mhi;                                    \
    }                                                                            \
    _Pragma("unroll")                                                            \
    for (int ks = 0; ks < 2; ++ks) {                                             \
      unsigned mm = ks ? mhi : mlo;                                              \
      unsigned byt = (mm >> (kgrp << 3)) & 0xffu;                                \
      int jloc = (TI) * 64 + ks * 32 + kgrp * 8;                                 \
      f32x4 sa = *(const f32x4*)&s2l[jloc];                                      \
      f32x4 sb = *(const f32x4*)&s2l[jloc + 4];                                  \
      f16x8 af;                                                                  \
      af[0] = wel(byt & 1u,   sa[0], s10, m0, sum0);                             \
      af[1] = wel(byt & 2u,   sa[1], s10, m0, sum0);                             \
      af[2] = wel(byt & 4u,   sa[2], s10, m0, sum0);                             \
      af[3] = wel(byt & 8u,   sa[3], s10, m0, sum0);                             \
      af[4] = wel(byt & 16u,  sb[0], s10, m0, sum0);                             \
      af[5] = wel(byt & 32u,  sb[1], s10, m0, sum0);                             \
      af[6] = wel(byt & 64u,  sb[2], s10, m0, sum0);                             \
      af[7] = wel(byt & 128u, sb[3], s10, m0, sum0);                             \
      _Pragma("unroll")                                                          \
      for (int cf = 0; cf < 8; ++cf) {                                           \
        f16x8 bfr = *(const f16x8*)&tile[buf][(cf * 16 + l15) * 64 +             \
                       ((ks * 32 + kgrp * 8) ^ (l7 * 8))];                       \
        acc[cf] = __builtin_amdgcn_mfma_f32_16x16x32_f16(af, bfr, acc[cf], 0, 0, 0); \
      }                                                                          \
    }                                                                            \
  }

// ---------------- K4: fully fused attention x h, adj read STREAMING ----------
// grid (SPLITK=8 splits, 128 row-blocks), 256 threads = 4 waves x 16 rows.
// Each wave reads its 16 adj rows as 16x (1 row x 256 B contiguous) instrs,
// distance-2 prefetched through a 3-set register rotation (ra/rb/rc).
// hT tile [128][64] fp16 double-buffered via global_load_lds, both-sides
// XOR swizzle (slot ^= row&7). Exactly one vmcnt(16)+s_barrier per body.
__global__ void __launch_bounds__(256, 4) k4_main(
    const int* __restrict__ adj, const float* __restrict__ s1g,
    const float* __restrict__ s2g, const unsigned* __restrict__ enc,
    const _Float16* __restrict__ hT,
    float* __restrict__ num_p, float* __restrict__ den_p) {
  __shared__ _Float16 tile[2][128 * 64];
  __shared__ float s2l[JCH];
  int t = threadIdx.x;
  int l = t & 63, wv = t >> 6;
  int l15 = l & 15, kgrp = l >> 4;
  int l7 = l15 & 7;
  int split = blockIdx.x;
  int r0 = blockIdx.y * 64;
  int jbeg = split * JCH;
  int row = r0 + wv * 16 + l15;

  float c2 = dec_f32(*enc);
  float s10 = s1g[row];
  float m0 = s10 + c2; m0 = fmaxf(m0, 0.01f * m0);

  f32x4 acc[8];
#pragma unroll
  for (int cf = 0; cf < 8; ++cf) acc[cf] = (f32x4){0.f, 0.f, 0.f, 0.f};
  float sum0 = 0.f;
  const int* abase = adj + (size_t)(r0 + wv * 16) * NN + l;  // wave's row 0, col l

  // stage [128][64] tile, wave wv covers rows wv*32..+31; linear LDS dest,
  // global col slot pre-XOR'd with row&7 (= l>>3, invariant across +8k rows).
  auto stage = [&](int b, int jg) {
    const _Float16* g0 = hT + (size_t)(wv * 32 + (l >> 3)) * NN + jg +
                         (((l & 7) ^ (l >> 3)) * 8);
    _Float16* base = &tile[b][(wv * 32) * 64];
    gl_lds16(g0, base);
    gl_lds16(g0 + (size_t)8 * NN, base + 8 * 64);
    gl_lds16(g0 + (size_t)16 * NN, base + 16 * 64);
    gl_lds16(g0 + (size_t)24 * NN, base + 24 * 64);
  };

  // ---- prologue: stage buf0, s2 slice -> LDS, adj for bodies 0 and 1 ----
  int ra[16], rb[16], rc[16];
  int buf = 0;
  stage(0, jbeg);
  LOADSET(ra, jbeg)
  LOADSET(rb, jbeg + 64)
  *(float4*)&s2l[t * 4] = *(const float4*)(s2g + jbeg + t * 4);
  // drain stage0 + ra (leave rb in flight); lgkm for the s2l ds_writes
  asm volatile("s_waitcnt vmcnt(16) lgkmcnt(0)" ::: "memory");
  __builtin_amdgcn_s_barrier();
  __builtin_amdgcn_sched_barrier(0);

  // bodies 0..11: 4 iterations x 3-body rotation (consume ra,rb,rc; load rc,ra,rb)
#pragma unroll 1
  for (int tI = 0; tI < 12; tI += 3) {
    K4BODY(ra, rc, tI,     true, 16);
    K4BODY(rb, ra, tI + 1, true, 16);
    K4BODY(rc, rb, tI + 2, true, 16);
  }
  // bodies 12..15 (tail: body14 no load + full drain, body15 last)
  K4BODY(ra, rc, 12, true, 16);
  K4BODY(rb, ra, 13, true, 16);
  K4BODY(rc, rb, 14, false, 0);
  K4LAST(ra, 15);

  // row sums: lanes kgrp 0..3 of same l15 combine
  sum0 += __shfl_xor(sum0, 16);
  sum0 += __shfl_xor(sum0, 32);
  size_t sbase = (size_t)split * NN;
  if (l < 16) den_p[sbase + r0 + wv * 16 + l] = sum0;
  // C/D layout: col = l&15, row = kgrp*4 + i
#pragma unroll
  for (int cf = 0; cf < 8; ++cf) {
#pragma unroll
    for (int i = 0; i < 4; ++i) {
      int orow = r0 + wv * 16 + kgrp * 4 + i;
      int ocol = cf * 16 + l15;
      num_p[(sbase + orow) * (size_t)FO + ocol] = acc[cf][i];
    }
  }
}

// ---------------- K5: finalize out = elu(sum(num)/sum(den)) ----------------
__global__ void k5_fin(const float* __restrict__ num_p, const float* __restrict__ den_p,
                       float* __restrict__ out) {
  int idx = blockIdx.x * 256 + threadIdx.x;
  int row = idx >> 7;
  float num = 0.f, den = 0.f;
#pragma unroll
  for (int s = 0; s < SPLITK; ++s) {
    num += num_p[(size_t)s * (NN * FO) + idx];
    den += den_p[(size_t)s * NN + row];
  }
  float v = num / den;
  out[idx] = v > 0.f ? v : expm1f(v);
}

extern "C" void kernel_launch(void* const* d_in, const int* in_sizes, int n_in,
                              void* d_out, int out_size, void* d_ws, size_t ws_size,
                              hipStream_t stream) {
  const float* x   = (const float*)d_in[0];
  const int*   adj = (const int*)d_in[1];
  const float* W   = (const float*)d_in[2];
  const float* a   = (const float*)d_in[3];
  float* out = (float*)d_out;
  char* ws = (char*)d_ws;

  float*     h     = (float*)ws;                                   // 4 MB
  _Float16*  hT    = (_Float16*)(ws + ((size_t)4 << 20));          // 2 MB
  float*     s1    = (float*)(ws + ((size_t)6 << 20));             // 32 KB
  float*     s2    = (float*)(ws + ((size_t)6 << 20) + (32u << 10));
  unsigned*  enc   = (unsigned*)(ws + ((size_t)6 << 20) + (64u << 10));
  float*     den_p = (float*)(ws + ((size_t)6 << 20) + (128u << 10)); // 256 KB
  float*     num_p = (float*)(ws + ((size_t)7 << 20));             // 8 * 4 MB

  k1_xw<<<dim3(256), dim3(256), 0, stream>>>(x, W, h, enc);
  k2_prep<<<dim3(128), dim3(256), 0, stream>>>(h, a, hT, s1, s2, enc);
  k4_main<<<dim3(SPLITK, 128), dim3(256), 0, stream>>>(adj, s1, s2, enc, hT,
                                                       num_p, den_p);
  k5_fin<<<dim3((NN * FO) / 256), dim3(256), 0, stream>>>(num_p, den_p, out);
}

// Round 8
// 136.429 us; speedup vs baseline: 1.2574x; 1.2574x over previous
//
#include <hip/hip_runtime.h>
#include <hip/hip_bf16.h>
#include <cstdint>
#include <cstddef>

#define NN 8192
#define FIN 256
#define FO 128
#define SPLITK 8
#define JCH 1024   // NN / SPLITK
#define NIT 16     // JCH / 64

typedef float f32x4 __attribute__((ext_vector_type(4)));
typedef _Float16 f16x8 __attribute__((ext_vector_type(8)));

typedef __attribute__((address_space(3))) void lds_void;
typedef const __attribute__((address_space(1))) void glb_void;
__device__ __forceinline__ void gl_lds16(const void* g, void* l) {
  __builtin_amdgcn_global_load_lds((glb_void*)g, (lds_void*)l, 16, 0, 0);
}

__device__ __forceinline__ unsigned enc_f32(float f) {
  unsigned u = __float_as_uint(f);
  return (u & 0x80000000u) ? ~u : (u | 0x80000000u);
}
__device__ __forceinline__ float dec_f32(unsigned u) {
  unsigned b = (u & 0x80000000u) ? (u ^ 0x80000000u) : ~u;
  return __uint_as_float(b);
}

// ---------------- K0: compress adj (int32 0/1) -> row-major bitmask ------------
// One wave per row; lane l reads adj[row][j0+l]: contiguous 256 B wave-granules
// walking each row sequentially -> streaming HBM efficiency (proven round 4).
__global__ void __launch_bounds__(256) k0_bits(const int* __restrict__ adj,
                                               unsigned long long* __restrict__ bits) {
  int row = blockIdx.x * 4 + (threadIdx.x >> 6);
  int l = threadIdx.x & 63;
  const int* rowp = adj + (size_t)row * NN + l;
  unsigned long long* outp = bits + (size_t)row * (NN / 64);
#pragma unroll 2
  for (int j0 = 0; j0 < NN; j0 += 256) {
    int v0 = rowp[j0];
    int v1 = rowp[j0 + 64];
    int v2 = rowp[j0 + 128];
    int v3 = rowp[j0 + 192];
    unsigned long long m0 = __ballot(v0 > 0);
    unsigned long long m1 = __ballot(v1 > 0);
    unsigned long long m2 = __ballot(v2 > 0);
    unsigned long long m3 = __ballot(v3 > 0);
    if (l == 0) {
      outp[(j0 >> 6) + 0] = m0;
      outp[(j0 >> 6) + 1] = m1;
      outp[(j0 >> 6) + 2] = m2;
      outp[(j0 >> 6) + 3] = m3;
    }
  }
}

// ---------------- K1: h = x @ W  (8192x256 @ 256x128) ----------------
__global__ void k1_xw(const float* __restrict__ x, const float* __restrict__ W,
                      float* __restrict__ h, unsigned* __restrict__ enc) {
  __shared__ float xs[32 * 66];
  __shared__ float Ws[64 * 128];
  int t = threadIdx.x;
  int r0 = blockIdx.x * 32;
  if (blockIdx.x == 0 && t == 0) *enc = 0u;  // init for K2's atomicMax
  int r = t & 31, cg = t >> 5;
  float acc[16];
#pragma unroll
  for (int i = 0; i < 16; ++i) acc[i] = 0.f;
  for (int ko = 0; ko < 4; ++ko) {
    __syncthreads();
    {
      int rr = t >> 3, kc = (t & 7) * 8;
      const float2* src = (const float2*)(x + (size_t)(r0 + rr) * FIN + ko * 64 + kc);
      float2* dst = (float2*)&xs[rr * 66 + kc];
#pragma unroll
      for (int q = 0; q < 4; ++q) dst[q] = src[q];
    }
    {
      int kk = t >> 2, q = t & 3;
      const float4* src = (const float4*)(W + (size_t)(ko * 64 + kk) * FO + q * 32);
      float4* dst = (float4*)&Ws[kk * 128 + q * 32];
#pragma unroll
      for (int i = 0; i < 8; ++i) dst[i] = src[i];
    }
    __syncthreads();
#pragma unroll 8
    for (int kk = 0; kk < 64; ++kk) {
      float xv = xs[r * 66 + kk];
      const float4* wr = (const float4*)&Ws[kk * 128 + cg * 16];
      float4 w0 = wr[0], w1 = wr[1], w2 = wr[2], w3 = wr[3];
      acc[0]  = fmaf(xv, w0.x, acc[0]);  acc[1]  = fmaf(xv, w0.y, acc[1]);
      acc[2]  = fmaf(xv, w0.z, acc[2]);  acc[3]  = fmaf(xv, w0.w, acc[3]);
      acc[4]  = fmaf(xv, w1.x, acc[4]);  acc[5]  = fmaf(xv, w1.y, acc[5]);
      acc[6]  = fmaf(xv, w1.z, acc[6]);  acc[7]  = fmaf(xv, w1.w, acc[7]);
      acc[8]  = fmaf(xv, w2.x, acc[8]);  acc[9]  = fmaf(xv, w2.y, acc[9]);
      acc[10] = fmaf(xv, w2.z, acc[10]); acc[11] = fmaf(xv, w2.w, acc[11]);
      acc[12] = fmaf(xv, w3.x, acc[12]); acc[13] = fmaf(xv, w3.y, acc[13]);
      acc[14] = fmaf(xv, w3.z, acc[14]); acc[15] = fmaf(xv, w3.w, acc[15]);
    }
  }
  float* hp = h + (size_t)(r0 + r) * FO + cg * 16;
#pragma unroll
  for (int i = 0; i < 4; ++i)
    ((float4*)hp)[i] = make_float4(acc[4 * i], acc[4 * i + 1], acc[4 * i + 2], acc[4 * i + 3]);
}

// ---------------- K2: hT (fp16 transpose), s1, s2, max(s2) ----------------
__global__ void k2_prep(const float* __restrict__ h, const float* __restrict__ a,
                        _Float16* __restrict__ hT,
                        float* __restrict__ s1, float* __restrict__ s2,
                        unsigned* __restrict__ enc) {
  __shared__ float ht[64 * 129];
  int t = threadIdx.x;
  int r0 = blockIdx.x * 64;
  {
    int rr = t >> 2, q = t & 3;
    const float4* src = (const float4*)(h + (size_t)(r0 + rr) * FO + q * 32);
    float* dst = &ht[rr * 129 + q * 32];
#pragma unroll
    for (int i = 0; i < 8; ++i) {
      float4 v = src[i];
      dst[4 * i + 0] = v.x; dst[4 * i + 1] = v.y;
      dst[4 * i + 2] = v.z; dst[4 * i + 3] = v.w;
    }
  }
  __syncthreads();
  {
    int c = t >> 1, half = t & 1;
    alignas(16) _Float16 buf[32];
#pragma unroll
    for (int i = 0; i < 32; ++i) buf[i] = (_Float16)ht[(half * 32 + i) * 129 + c];
    int4* d = (int4*)(hT + (size_t)c * NN + r0 + half * 32);
#pragma unroll
    for (int i = 0; i < 4; ++i) d[i] = ((const int4*)buf)[i];
  }
  if (t < 64) {
    int row = r0 + t;
    float v1 = 0.f, v2 = 0.f;
#pragma unroll 16
    for (int c = 0; c < FO; ++c) {
      float hv = ht[t * 129 + c];
      v1 = fmaf(hv, a[c], v1);
      v2 = fmaf(hv, a[FO + c], v2);
    }
    s1[row] = v1; s2[row] = v2;
    float m = v2;
#pragma unroll
    for (int off = 1; off < 64; off <<= 1) m = fmaxf(m, __shfl_xor(m, off));
    if (t == 0) atomicMax(enc, enc_f32(m));
  }
}

// weight: w = bit ? exp(leaky(s1+s2) - m) : 0, rounded to fp16;
// den accumulates the *rounded* weight in f32 for exact normalization consistency.
__device__ __forceinline__ _Float16 wel(unsigned av, float s2v, float s1v, float mv, float& sum) {
  float tt = s1v + s2v;
  tt = fmaxf(tt, 0.01f * tt);  // leaky_relu
  float wf = av ? __expf(tt - mv) : 0.f;
  _Float16 wh = (_Float16)wf;
  sum += (float)wh;
  return wh;
}

// One j-step of 64 cols. CURBW holds this body's 64-bit row-mask (drained by the
// previous body's end-wait). Extract bytes FIRST, then reuse the register for
// the distance-2 reload. Exactly one vmcnt + s_barrier per body.
#define K4BODY(CURBW, TI, DOLOAD, ENDW)                                          \
  {                                                                              \
    stage(buf ^ 1, jbeg + ((TI) + 1) * 64);                                      \
    unsigned byt0 = (unsigned)(CURBW >> (kgrp * 8)) & 0xffu;                     \
    unsigned byt1 = (unsigned)(CURBW >> (32 + kgrp * 8)) & 0xffu;                \
    if (DOLOAD) CURBW = brow[(TI) + 2];                                          \
    __builtin_amdgcn_sched_barrier(0);                                           \
    K4COMPUTE(byt0, byt1, TI)                                                    \
    __builtin_amdgcn_sched_barrier(0);                                           \
    asm volatile("s_waitcnt vmcnt(" #ENDW ")" ::: "memory");                     \
    __builtin_amdgcn_s_barrier();                                                \
    __builtin_amdgcn_sched_barrier(0);                                           \
    buf ^= 1;                                                                    \
  }

#define K4LAST(CURBW, TI)                                                        \
  {                                                                              \
    unsigned byt0 = (unsigned)(CURBW >> (kgrp * 8)) & 0xffu;                     \
    unsigned byt1 = (unsigned)(CURBW >> (32 + kgrp * 8)) & 0xffu;                \
    K4COMPUTE(byt0, byt1, TI)                                                    \
  }

#define K4COMPUTE(B0, B1, TI)                                                    \
  {                                                                              \
    _Pragma("unroll")                                                            \
    for (int ks = 0; ks < 2; ++ks) {                                             \
      unsigned byt = ks ? (B1) : (B0);                                           \
      int jloc = (TI) * 64 + ks * 32 + kgrp * 8;                                 \
      f32x4 sa = *(const f32x4*)&s2l[jloc];                                      \
      f32x4 sb = *(const f32x4*)&s2l[jloc + 4];                                  \
      f16x8 af;                                                                  \
      af[0] = wel(byt & 1u,   sa[0], s10, m0, sum0);                             \
      af[1] = wel(byt & 2u,   sa[1], s10, m0, sum0);                             \
      af[2] = wel(byt & 4u,   sa[2], s10, m0, sum0);                             \
      af[3] = wel(byt & 8u,   sa[3], s10, m0, sum0);                             \
      af[4] = wel(byt & 16u,  sb[0], s10, m0, sum0);                             \
      af[5] = wel(byt & 32u,  sb[1], s10, m0, sum0);                             \
      af[6] = wel(byt & 64u,  sb[2], s10, m0, sum0);                             \
      af[7] = wel(byt & 128u, sb[3], s10, m0, sum0);                             \
      _Pragma("unroll")                                                          \
      for (int cf = 0; cf < 8; ++cf) {                                           \
        f16x8 bfr = *(const f16x8*)&tile[buf][(cf * 16 + l15) * 64 +             \
                       ((ks * 32 + kgrp * 8) ^ (l7 * 8))];                       \
        acc[cf] = __builtin_amdgcn_mfma_f32_16x16x32_f16(af, bfr, acc[cf], 0, 0, 0); \
      }                                                                          \
    }                                                                            \
  }

// ---------------- K4: fused attention x h from L2-resident BITMASK -----------
// grid (SPLITK=8 splits, 128 row-blocks), 256 threads = 4 waves x 16 rows.
// Per body: 1 dwordx2 bits load/lane + 4 gl_lds stage. Round-6 chassis:
// [128][64] fp16 tile double-buffered, both-sides XOR swizzle (slot ^= row&7),
// distance-2 bits prefetch in 2 alternating ulongs, one vmcnt(1)+barrier/body.
__global__ void __launch_bounds__(256, 4) k4_main(
    const unsigned long long* __restrict__ bits, const float* __restrict__ s1g,
    const float* __restrict__ s2g, const unsigned* __restrict__ enc,
    const _Float16* __restrict__ hT,
    float* __restrict__ num_p, float* __restrict__ den_p) {
  __shared__ _Float16 tile[2][128 * 64];
  __shared__ float s2l[JCH];
  int t = threadIdx.x;
  int l = t & 63, wv = t >> 6;
  int l15 = l & 15, kgrp = l >> 4;
  int l7 = l15 & 7;
  int split = blockIdx.x;
  int r0 = blockIdx.y * 64;
  int jbeg = split * JCH;
  int row = r0 + wv * 16 + l15;

  float c2 = dec_f32(*enc);
  float s10 = s1g[row];
  float m0 = s10 + c2; m0 = fmaxf(m0, 0.01f * m0);

  f32x4 acc[8];
#pragma unroll
  for (int cf = 0; cf < 8; ++cf) acc[cf] = (f32x4){0.f, 0.f, 0.f, 0.f};
  float sum0 = 0.f;
  // this row's bit-words for this split: word tI = cols jbeg + tI*64
  const unsigned long long* brow = bits + (size_t)row * (NN / 64) + (jbeg >> 6);

  // stage [128][64] tile, wave wv covers rows wv*32..+31; linear LDS dest,
  // global col slot pre-XOR'd with row&7 (= l>>3, invariant across +8k rows).
  auto stage = [&](int b, int jg) {
    const _Float16* g0 = hT + (size_t)(wv * 32 + (l >> 3)) * NN + jg +
                         (((l & 7) ^ (l >> 3)) * 8);
    _Float16* base = &tile[b][(wv * 32) * 64];
    gl_lds16(g0, base);
    gl_lds16(g0 + (size_t)8 * NN, base + 8 * 64);
    gl_lds16(g0 + (size_t)16 * NN, base + 16 * 64);
    gl_lds16(g0 + (size_t)24 * NN, base + 24 * 64);
  };

  // ---- prologue: stage buf0, s2 slice -> LDS, bits for bodies 0 and 1 ----
  int buf = 0;
  stage(0, jbeg);
  unsigned long long bwA = brow[0];
  unsigned long long bwB = brow[1];
  *(float4*)&s2l[t * 4] = *(const float4*)(s2g + jbeg + t * 4);
  // drain stage0 + bwA (keep bwB in flight); lgkm for the s2l ds_writes
  asm volatile("s_waitcnt vmcnt(1) lgkmcnt(0)" ::: "memory");
  __builtin_amdgcn_s_barrier();
  __builtin_amdgcn_sched_barrier(0);

  // bodies 0..13: consume bwA/bwB alternately, reload same reg at distance 2
#pragma unroll 1
  for (int tI = 0; tI < 14; tI += 2) {
    K4BODY(bwA, tI, true, 1);
    K4BODY(bwB, tI + 1, true, 1);
  }
  // body 14 (stages body-15 tile, no further bits load, full drain), body 15
  K4BODY(bwA, 14, false, 0);
  K4LAST(bwB, 15);

  // row sums: lanes kgrp 0..3 of same l15 combine
  sum0 += __shfl_xor(sum0, 16);
  sum0 += __shfl_xor(sum0, 32);
  size_t sbase = (size_t)split * NN;
  if (l < 16) den_p[sbase + r0 + wv * 16 + l] = sum0;
  // C/D layout: col = l&15, row = kgrp*4 + i
#pragma unroll
  for (int cf = 0; cf < 8; ++cf) {
#pragma unroll
    for (int i = 0; i < 4; ++i) {
      int orow = r0 + wv * 16 + kgrp * 4 + i;
      int ocol = cf * 16 + l15;
      num_p[(sbase + orow) * (size_t)FO + ocol] = acc[cf][i];
    }
  }
}

// ---------------- K5: finalize out = elu(sum(num)/sum(den)) ----------------
__global__ void k5_fin(const float* __restrict__ num_p, const float* __restrict__ den_p,
                       float* __restrict__ out) {
  int idx = blockIdx.x * 256 + threadIdx.x;
  int row = idx >> 7;
  float num = 0.f, den = 0.f;
#pragma unroll
  for (int s = 0; s < SPLITK; ++s) {
    num += num_p[(size_t)s * (NN * FO) + idx];
    den += den_p[(size_t)s * NN + row];
  }
  float v = num / den;
  out[idx] = v > 0.f ? v : expm1f(v);
}

extern "C" void kernel_launch(void* const* d_in, const int* in_sizes, int n_in,
                              void* d_out, int out_size, void* d_ws, size_t ws_size,
                              hipStream_t stream) {
  const float* x   = (const float*)d_in[0];
  const int*   adj = (const int*)d_in[1];
  const float* W   = (const float*)d_in[2];
  const float* a   = (const float*)d_in[3];
  float* out = (float*)d_out;
  char* ws = (char*)d_ws;

  float*     h     = (float*)ws;                                   // 4 MB
  _Float16*  hT    = (_Float16*)(ws + ((size_t)4 << 20));          // 2 MB
  float*     s1    = (float*)(ws + ((size_t)6 << 20));             // 32 KB
  float*     s2    = (float*)(ws + ((size_t)6 << 20) + (32u << 10));
  unsigned*  enc   = (unsigned*)(ws + ((size_t)6 << 20) + (64u << 10));
  float*     den_p = (float*)(ws + ((size_t)6 << 20) + (128u << 10)); // 256 KB
  float*     num_p = (float*)(ws + ((size_t)7 << 20));             // 8 * 4 MB -> ends 39 MB
  unsigned long long* bits = (unsigned long long*)(ws + ((size_t)40 << 20)); // 8.4 MB

  k0_bits<<<dim3(NN / 4), dim3(256), 0, stream>>>(adj, bits);
  k1_xw<<<dim3(256), dim3(256), 0, stream>>>(x, W, h, enc);
  k2_prep<<<dim3(128), dim3(256), 0, stream>>>(h, a, hT, s1, s2, enc);
  k4_main<<<dim3(SPLITK, 128), dim3(256), 0, stream>>>(bits, s1, s2, enc, hT,
                                                       num_p, den_p);
  k5_fin<<<dim3((NN * FO) / 256), dim3(256), 0, stream>>>(num_p, den_p, out);
}

// Round 9
// 120.220 us; speedup vs baseline: 1.4270x; 1.1348x over previous
//
#include <hip/hip_runtime.h>
#include <hip/hip_bf16.h>
#include <cstdint>
#include <cstddef>

#define NN 8192
#define FIN 256
#define FO 128
#define SPLITK 8
#define JCH 1024   // NN / SPLITK
#define NSB 8      // superbodies per block (2 bodies each, 128 j per superbody)

typedef float f32x4 __attribute__((ext_vector_type(4)));
typedef _Float16 f16x8 __attribute__((ext_vector_type(8)));

typedef __attribute__((address_space(3))) void lds_void;
typedef const __attribute__((address_space(1))) void glb_void;
__device__ __forceinline__ void gl_lds16(const void* g, void* l) {
  __builtin_amdgcn_global_load_lds((glb_void*)g, (lds_void*)l, 16, 0, 0);
}

__device__ __forceinline__ unsigned enc_f32(float f) {
  unsigned u = __float_as_uint(f);
  return (u & 0x80000000u) ? ~u : (u | 0x80000000u);
}
__device__ __forceinline__ float dec_f32(unsigned u) {
  unsigned b = (u & 0x80000000u) ? (u ^ 0x80000000u) : ~u;
  return __uint_as_float(b);
}

// ---------------- K1: h = x @ W  (8192x256 @ 256x128) ----------------
__global__ void k1_xw(const float* __restrict__ x, const float* __restrict__ W,
                      float* __restrict__ h, unsigned* __restrict__ enc) {
  __shared__ float xs[32 * 66];
  __shared__ float Ws[64 * 128];
  int t = threadIdx.x;
  int r0 = blockIdx.x * 32;
  if (blockIdx.x == 0 && t == 0) *enc = 0u;  // init for K2's atomicMax
  int r = t & 31, cg = t >> 5;
  float acc[16];
#pragma unroll
  for (int i = 0; i < 16; ++i) acc[i] = 0.f;
  for (int ko = 0; ko < 4; ++ko) {
    __syncthreads();
    {
      int rr = t >> 3, kc = (t & 7) * 8;
      const float2* src = (const float2*)(x + (size_t)(r0 + rr) * FIN + ko * 64 + kc);
      float2* dst = (float2*)&xs[rr * 66 + kc];
#pragma unroll
      for (int q = 0; q < 4; ++q) dst[q] = src[q];
    }
    {
      int kk = t >> 2, q = t & 3;
      const float4* src = (const float4*)(W + (size_t)(ko * 64 + kk) * FO + q * 32);
      float4* dst = (float4*)&Ws[kk * 128 + q * 32];
#pragma unroll
      for (int i = 0; i < 8; ++i) dst[i] = src[i];
    }
    __syncthreads();
#pragma unroll 8
    for (int kk = 0; kk < 64; ++kk) {
      float xv = xs[r * 66 + kk];
      const float4* wr = (const float4*)&Ws[kk * 128 + cg * 16];
      float4 w0 = wr[0], w1 = wr[1], w2 = wr[2], w3 = wr[3];
      acc[0]  = fmaf(xv, w0.x, acc[0]);  acc[1]  = fmaf(xv, w0.y, acc[1]);
      acc[2]  = fmaf(xv, w0.z, acc[2]);  acc[3]  = fmaf(xv, w0.w, acc[3]);
      acc[4]  = fmaf(xv, w1.x, acc[4]);  acc[5]  = fmaf(xv, w1.y, acc[5]);
      acc[6]  = fmaf(xv, w1.z, acc[6]);  acc[7]  = fmaf(xv, w1.w, acc[7]);
      acc[8]  = fmaf(xv, w2.x, acc[8]);  acc[9]  = fmaf(xv, w2.y, acc[9]);
      acc[10] = fmaf(xv, w2.z, acc[10]); acc[11] = fmaf(xv, w2.w, acc[11]);
      acc[12] = fmaf(xv, w3.x, acc[12]); acc[13] = fmaf(xv, w3.y, acc[13]);
      acc[14] = fmaf(xv, w3.z, acc[14]); acc[15] = fmaf(xv, w3.w, acc[15]);
    }
  }
  float* hp = h + (size_t)(r0 + r) * FO + cg * 16;
#pragma unroll
  for (int i = 0; i < 4; ++i)
    ((float4*)hp)[i] = make_float4(acc[4 * i], acc[4 * i + 1], acc[4 * i + 2], acc[4 * i + 3]);
}

// ---------------- K2: hT (fp16 transpose), s1, s2, max(s2) ----------------
__global__ void k2_prep(const float* __restrict__ h, const float* __restrict__ a,
                        _Float16* __restrict__ hT,
                        float* __restrict__ s1, float* __restrict__ s2,
                        unsigned* __restrict__ enc) {
  __shared__ float ht[64 * 129];
  int t = threadIdx.x;
  int r0 = blockIdx.x * 64;
  {
    int rr = t >> 2, q = t & 3;
    const float4* src = (const float4*)(h + (size_t)(r0 + rr) * FO + q * 32);
    float* dst = &ht[rr * 129 + q * 32];
#pragma unroll
    for (int i = 0; i < 8; ++i) {
      float4 v = src[i];
      dst[4 * i + 0] = v.x; dst[4 * i + 1] = v.y;
      dst[4 * i + 2] = v.z; dst[4 * i + 3] = v.w;
    }
  }
  __syncthreads();
  {
    int c = t >> 1, half = t & 1;
    alignas(16) _Float16 buf[32];
#pragma unroll
    for (int i = 0; i < 32; ++i) buf[i] = (_Float16)ht[(half * 32 + i) * 129 + c];
    int4* d = (int4*)(hT + (size_t)c * NN + r0 + half * 32);
#pragma unroll
    for (int i = 0; i < 4; ++i) d[i] = ((const int4*)buf)[i];
  }
  if (t < 64) {
    int row = r0 + t;
    float v1 = 0.f, v2 = 0.f;
#pragma unroll 16
    for (int c = 0; c < FO; ++c) {
      float hv = ht[t * 129 + c];
      v1 = fmaf(hv, a[c], v1);
      v2 = fmaf(hv, a[FO + c], v2);
    }
    s1[row] = v1; s2[row] = v2;
    float m = v2;
#pragma unroll
    for (int off = 1; off < 64; off <<= 1) m = fmaxf(m, __shfl_xor(m, off));
    if (t == 0) atomicMax(enc, enc_f32(m));
  }
}

// weight: w = bit ? exp(leaky(s1+s2) - m) : 0, rounded to fp16;
// den accumulates the *rounded* weight in f32 for exact normalization consistency.
__device__ __forceinline__ _Float16 wel(unsigned av, float s2v, float s1v, float mv, float& sum) {
  float tt = s1v + s2v;
  tt = fmaxf(tt, 0.01f * tt);  // leaky_relu
  float wf = av ? __expf(tt - mv) : 0.f;
  _Float16 wh = (_Float16)wf;
  sum += (float)wh;
  return wh;
}

// Compute one body (64 j). MEV/MOD: this body's 32-bit even/odd col masks.
// af[e] <-> col jbody + ks*32 + kgrp*8 + e; even cols in MEV, odd in MOD,
// bit index = (col within body)/2.
#define K4COMPUTE(MEV, MOD, BUFI, SBASE)                                         \
  {                                                                              \
    _Pragma("unroll")                                                            \
    for (int ks = 0; ks < 2; ++ks) {                                             \
      unsigned ne = ((MEV) >> (ks * 16 + kgrp * 4)) & 0xfu;                      \
      unsigned no = ((MOD) >> (ks * 16 + kgrp * 4)) & 0xfu;                      \
      int jloc = (SBASE) + ks * 32 + kgrp * 8;                                   \
      f32x4 sa = *(const f32x4*)&s2l[jloc];                                      \
      f32x4 sb = *(const f32x4*)&s2l[jloc + 4];                                  \
      f16x8 af;                                                                  \
      af[0] = wel(ne & 1u, sa[0], s10, m0, sum0);                                \
      af[1] = wel(no & 1u, sa[1], s10, m0, sum0);                                \
      af[2] = wel(ne & 2u, sa[2], s10, m0, sum0);                                \
      af[3] = wel(no & 2u, sa[3], s10, m0, sum0);                                \
      af[4] = wel(ne & 4u, sb[0], s10, m0, sum0);                                \
      af[5] = wel(no & 4u, sb[1], s10, m0, sum0);                                \
      af[6] = wel(ne & 8u, sb[2], s10, m0, sum0);                                \
      af[7] = wel(no & 8u, sb[3], s10, m0, sum0);                                \
      _Pragma("unroll")                                                          \
      for (int cf = 0; cf < 8; ++cf) {                                           \
        f16x8 bfr = *(const f16x8*)&tile[BUFI][(cf * 16 + l15) * 64 +            \
                       ((ks * 32 + kgrp * 8) ^ (l7 * 8))];                       \
        acc[cf] = __builtin_amdgcn_mfma_f32_16x16x32_f16(af, bfr, acc[cf], 0, 0, 0); \
      }                                                                          \
    }                                                                            \
  }

// ---------------- K4: fused attention x h, adj in 512B bursts -----------------
// grid (SPLITK=8 splits, 128 row-blocks), 256 threads = 4 waves x 16 rows.
// Superbody = 128 j = 2 bodies. Per superbody each wave issues 16 int2 loads:
// ONE instruction = one row x 512 B CONTIGUOUS (page-efficient burst).
// Ballot x2 per row at superbody start -> 4 lane-local mask words (even/odd
// cols x lo/hi body). hT tile [128][64] fp16 double-buffered via gl_lds with
// both-sides XOR swizzle. Even body: vmcnt(16) keeps adj in flight; odd body:
// vmcnt(0) at superbody boundary.
__global__ void __launch_bounds__(256, 4) k4_main(
    const int* __restrict__ adj, const float* __restrict__ s1g,
    const float* __restrict__ s2g, const unsigned* __restrict__ enc,
    const _Float16* __restrict__ hT,
    float* __restrict__ num_p, float* __restrict__ den_p) {
  __shared__ _Float16 tile[2][128 * 64];
  __shared__ float s2l[JCH];
  int t = threadIdx.x;
  int l = t & 63, wv = t >> 6;
  int l15 = l & 15, kgrp = l >> 4;
  int l7 = l15 & 7;
  int split = blockIdx.x;
  int r0 = blockIdx.y * 64;
  int jbeg = split * JCH;
  int row = r0 + wv * 16 + l15;

  float c2 = dec_f32(*enc);
  float s10 = s1g[row];
  float m0 = s10 + c2; m0 = fmaxf(m0, 0.01f * m0);

  f32x4 acc[8];
#pragma unroll
  for (int cf = 0; cf < 8; ++cf) acc[cf] = (f32x4){0.f, 0.f, 0.f, 0.f};
  float sum0 = 0.f;
  // wave's adj rows base; lane l covers cols (J + 2l, J + 2l + 1) as int2
  const int* abase = adj + (size_t)(r0 + wv * 16) * NN + 2 * l;

  auto stage = [&](int b, int jg) {
    const _Float16* g0 = hT + (size_t)(wv * 32 + (l >> 3)) * NN + jg +
                         (((l & 7) ^ (l >> 3)) * 8);
    _Float16* base = &tile[b][(wv * 32) * 64];
    gl_lds16(g0, base);
    gl_lds16(g0 + (size_t)8 * NN, base + 8 * 64);
    gl_lds16(g0 + (size_t)16 * NN, base + 16 * 64);
    gl_lds16(g0 + (size_t)24 * NN, base + 24 * 64);
  };

  int2 S[16];
#define LOADSET2(J)                                                              \
  _Pragma("unroll")                                                              \
  for (int rr = 0; rr < 16; ++rr)                                                \
    S[rr] = *(const int2*)(abase + (size_t)rr * NN + (J));

  // ballot loaded superbody -> per-lane masks (even/odd cols, lo/hi 32)
  unsigned mev_lo, mev_hi, mod_lo, mod_hi;
#define BALLOTROUTE()                                                            \
  {                                                                              \
    mev_lo = 0u; mev_hi = 0u; mod_lo = 0u; mod_hi = 0u;                          \
    _Pragma("unroll")                                                            \
    for (int rr = 0; rr < 16; ++rr) {                                            \
      unsigned long long be = __ballot(S[rr].x > 0);                             \
      unsigned long long bo = __ballot(S[rr].y > 0);                             \
      bool sel = (l15 == rr);                                                    \
      mev_lo = sel ? (unsigned)be : mev_lo;                                      \
      mev_hi = sel ? (unsigned)(be >> 32) : mev_hi;                              \
      mod_lo = sel ? (unsigned)bo : mod_lo;                                      \
      mod_hi = sel ? (unsigned)(bo >> 32) : mod_hi;                              \
    }                                                                            \
  }

  // ---- prologue: stage tile0, adj superbody 0, s2 slice ----
  stage(0, jbeg);
  LOADSET2(jbeg)
  *(float4*)&s2l[t * 4] = *(const float4*)(s2g + jbeg + t * 4);
  asm volatile("s_waitcnt vmcnt(0) lgkmcnt(0)" ::: "memory");
  __builtin_amdgcn_s_barrier();
  __builtin_amdgcn_sched_barrier(0);
  BALLOTROUTE()

#pragma unroll 1
  for (int sb = 0; sb < NSB; ++sb) {
    int sjb = jbeg + sb * 128;   // superbody global j base
    int sbase = sb * 128;        // superbody s2l base
    // ---- even body: cols sjb..sjb+63, tile[0] ----
    stage(1, sjb + 64);
    if (sb + 1 < NSB) { LOADSET2(sjb + 128) }
    __builtin_amdgcn_sched_barrier(0);
    K4COMPUTE(mev_lo, mod_lo, 0, sbase)
    __builtin_amdgcn_sched_barrier(0);
    if (sb + 1 < NSB) asm volatile("s_waitcnt vmcnt(16)" ::: "memory");
    else              asm volatile("s_waitcnt vmcnt(0)" ::: "memory");
    __builtin_amdgcn_s_barrier();
    __builtin_amdgcn_sched_barrier(0);
    // ---- odd body: cols sjb+64..sjb+127, tile[1] ----
    if (sb + 1 < NSB) stage(0, sjb + 128);
    __builtin_amdgcn_sched_barrier(0);
    K4COMPUTE(mev_hi, mod_hi, 1, sbase + 64)
    __builtin_amdgcn_sched_barrier(0);
    if (sb + 1 < NSB) {
      asm volatile("s_waitcnt vmcnt(0)" ::: "memory");
      __builtin_amdgcn_s_barrier();
      __builtin_amdgcn_sched_barrier(0);
      BALLOTROUTE()
    }
  }

  // row sums: lanes kgrp 0..3 of same l15 combine
  sum0 += __shfl_xor(sum0, 16);
  sum0 += __shfl_xor(sum0, 32);
  size_t sbase2 = (size_t)split * NN;
  if (l < 16) den_p[sbase2 + r0 + wv * 16 + l] = sum0;
  // C/D layout: col = l&15, row = kgrp*4 + i
#pragma unroll
  for (int cf = 0; cf < 8; ++cf) {
#pragma unroll
    for (int i = 0; i < 4; ++i) {
      int orow = r0 + wv * 16 + kgrp * 4 + i;
      int ocol = cf * 16 + l15;
      num_p[(sbase2 + orow) * (size_t)FO + ocol] = acc[cf][i];
    }
  }
}

// ---------------- K5: finalize out = elu(sum(num)/sum(den)) ----------------
__global__ void k5_fin(const float* __restrict__ num_p, const float* __restrict__ den_p,
                       float* __restrict__ out) {
  int idx = blockIdx.x * 256 + threadIdx.x;
  int row = idx >> 7;
  float num = 0.f, den = 0.f;
#pragma unroll
  for (int s = 0; s < SPLITK; ++s) {
    num += num_p[(size_t)s * (NN * FO) + idx];
    den += den_p[(size_t)s * NN + row];
  }
  float v = num / den;
  out[idx] = v > 0.f ? v : expm1f(v);
}

extern "C" void kernel_launch(void* const* d_in, const int* in_sizes, int n_in,
                              void* d_out, int out_size, void* d_ws, size_t ws_size,
                              hipStream_t stream) {
  const float* x   = (const float*)d_in[0];
  const int*   adj = (const int*)d_in[1];
  const float* W   = (const float*)d_in[2];
  const float* a   = (const float*)d_in[3];
  float* out = (float*)d_out;
  char* ws = (char*)d_ws;

  float*     h     = (float*)ws;                                   // 4 MB
  _Float16*  hT    = (_Float16*)(ws + ((size_t)4 << 20));          // 2 MB
  float*     s1    = (float*)(ws + ((size_t)6 << 20));             // 32 KB
  float*     s2    = (float*)(ws + ((size_t)6 << 20) + (32u << 10));
  unsigned*  enc   = (unsigned*)(ws + ((size_t)6 << 20) + (64u << 10));
  float*     den_p = (float*)(ws + ((size_t)6 << 20) + (128u << 10)); // 256 KB
  float*     num_p = (float*)(ws + ((size_t)7 << 20));             // 8 * 4 MB

  k1_xw<<<dim3(256), dim3(256), 0, stream>>>(x, W, h, enc);
  k2_prep<<<dim3(128), dim3(256), 0, stream>>>(h, a, hT, s1, s2, enc);
  k4_main<<<dim3(SPLITK, 128), dim3(256), 0, stream>>>(adj, s1, s2, enc, hT,
                                                       num_p, den_p);
  k5_fin<<<dim3((NN * FO) / 256), dim3(256), 0, stream>>>(num_p, den_p, out);
}

// Round 10
// 119.496 us; speedup vs baseline: 1.4356x; 1.0061x over previous
//
#include <hip/hip_runtime.h>
#include <hip/hip_bf16.h>
#include <cstdint>
#include <cstddef>

#define NN 8192
#define FIN 256
#define FO 128
#define SPLITK 8
#define JCH 1024   // NN / SPLITK
#define NSB 8      // superbodies per block (2 bodies each, 128 j per superbody)

typedef float f32x4 __attribute__((ext_vector_type(4)));
typedef _Float16 f16x8 __attribute__((ext_vector_type(8)));

typedef __attribute__((address_space(3))) void lds_void;
typedef const __attribute__((address_space(1))) void glb_void;
__device__ __forceinline__ void gl_lds16(const void* g, void* l) {
  __builtin_amdgcn_global_load_lds((glb_void*)g, (lds_void*)l, 16, 0, 0);
}

__device__ __forceinline__ unsigned enc_f32(float f) {
  unsigned u = __float_as_uint(f);
  return (u & 0x80000000u) ? ~u : (u | 0x80000000u);
}
__device__ __forceinline__ float dec_f32(unsigned u) {
  unsigned b = (u & 0x80000000u) ? (u ^ 0x80000000u) : ~u;
  return __uint_as_float(b);
}

// ---------------- K1: h = x @ W  (8192x256 @ 256x128) ----------------
__global__ void k1_xw(const float* __restrict__ x, const float* __restrict__ W,
                      float* __restrict__ h, unsigned* __restrict__ enc) {
  __shared__ float xs[32 * 66];
  __shared__ float Ws[64 * 128];
  int t = threadIdx.x;
  int r0 = blockIdx.x * 32;
  if (blockIdx.x == 0 && t == 0) *enc = 0u;  // init for K2's atomicMax
  int r = t & 31, cg = t >> 5;
  float acc[16];
#pragma unroll
  for (int i = 0; i < 16; ++i) acc[i] = 0.f;
  for (int ko = 0; ko < 4; ++ko) {
    __syncthreads();
    {
      int rr = t >> 3, kc = (t & 7) * 8;
      const float2* src = (const float2*)(x + (size_t)(r0 + rr) * FIN + ko * 64 + kc);
      float2* dst = (float2*)&xs[rr * 66 + kc];
#pragma unroll
      for (int q = 0; q < 4; ++q) dst[q] = src[q];
    }
    {
      int kk = t >> 2, q = t & 3;
      const float4* src = (const float4*)(W + (size_t)(ko * 64 + kk) * FO + q * 32);
      float4* dst = (float4*)&Ws[kk * 128 + q * 32];
#pragma unroll
      for (int i = 0; i < 8; ++i) dst[i] = src[i];
    }
    __syncthreads();
#pragma unroll 8
    for (int kk = 0; kk < 64; ++kk) {
      float xv = xs[r * 66 + kk];
      const float4* wr = (const float4*)&Ws[kk * 128 + cg * 16];
      float4 w0 = wr[0], w1 = wr[1], w2 = wr[2], w3 = wr[3];
      acc[0]  = fmaf(xv, w0.x, acc[0]);  acc[1]  = fmaf(xv, w0.y, acc[1]);
      acc[2]  = fmaf(xv, w0.z, acc[2]);  acc[3]  = fmaf(xv, w0.w, acc[3]);
      acc[4]  = fmaf(xv, w1.x, acc[4]);  acc[5]  = fmaf(xv, w1.y, acc[5]);
      acc[6]  = fmaf(xv, w1.z, acc[6]);  acc[7]  = fmaf(xv, w1.w, acc[7]);
      acc[8]  = fmaf(xv, w2.x, acc[8]);  acc[9]  = fmaf(xv, w2.y, acc[9]);
      acc[10] = fmaf(xv, w2.z, acc[10]); acc[11] = fmaf(xv, w2.w, acc[11]);
      acc[12] = fmaf(xv, w3.x, acc[12]); acc[13] = fmaf(xv, w3.y, acc[13]);
      acc[14] = fmaf(xv, w3.z, acc[14]); acc[15] = fmaf(xv, w3.w, acc[15]);
    }
  }
  float* hp = h + (size_t)(r0 + r) * FO + cg * 16;
#pragma unroll
  for (int i = 0; i < 4; ++i)
    ((float4*)hp)[i] = make_float4(acc[4 * i], acc[4 * i + 1], acc[4 * i + 2], acc[4 * i + 3]);
}

// ---------------- K2: hT (fp16 transpose), s1, s2, max(s2) ----------------
__global__ void k2_prep(const float* __restrict__ h, const float* __restrict__ a,
                        _Float16* __restrict__ hT,
                        float* __restrict__ s1, float* __restrict__ s2,
                        unsigned* __restrict__ enc) {
  __shared__ float ht[64 * 129];
  int t = threadIdx.x;
  int r0 = blockIdx.x * 64;
  {
    int rr = t >> 2, q = t & 3;
    const float4* src = (const float4*)(h + (size_t)(r0 + rr) * FO + q * 32);
    float* dst = &ht[rr * 129 + q * 32];
#pragma unroll
    for (int i = 0; i < 8; ++i) {
      float4 v = src[i];
      dst[4 * i + 0] = v.x; dst[4 * i + 1] = v.y;
      dst[4 * i + 2] = v.z; dst[4 * i + 3] = v.w;
    }
  }
  __syncthreads();
  {
    int c = t >> 1, half = t & 1;
    alignas(16) _Float16 buf[32];
#pragma unroll
    for (int i = 0; i < 32; ++i) buf[i] = (_Float16)ht[(half * 32 + i) * 129 + c];
    int4* d = (int4*)(hT + (size_t)c * NN + r0 + half * 32);
#pragma unroll
    for (int i = 0; i < 4; ++i) d[i] = ((const int4*)buf)[i];
  }
  if (t < 64) {
    int row = r0 + t;
    float v1 = 0.f, v2 = 0.f;
#pragma unroll 16
    for (int c = 0; c < FO; ++c) {
      float hv = ht[t * 129 + c];
      v1 = fmaf(hv, a[c], v1);
      v2 = fmaf(hv, a[FO + c], v2);
    }
    s1[row] = v1; s2[row] = v2;
    float m = v2;
#pragma unroll
    for (int off = 1; off < 64; off <<= 1) m = fmaxf(m, __shfl_xor(m, off));
    if (t == 0) atomicMax(enc, enc_f32(m));
  }
}

// weight: w = bit ? exp(leaky(s1+s2) - m) : 0, rounded to fp16;
// den accumulates the *rounded* weight in f32 for exact normalization consistency.
__device__ __forceinline__ _Float16 wel(unsigned av, float s2v, float s1v, float mv, float& sum) {
  float tt = s1v + s2v;
  tt = fmaxf(tt, 0.01f * tt);  // leaky_relu
  float wf = av ? __expf(tt - mv) : 0.f;
  _Float16 wh = (_Float16)wf;
  sum += (float)wh;
  return wh;
}

// Compute one body (64 j). MEV/MOD: this body's 32-bit even/odd col masks.
#define K4COMPUTE(MEV, MOD, BUFI, SBASE)                                         \
  {                                                                              \
    _Pragma("unroll")                                                            \
    for (int ks = 0; ks < 2; ++ks) {                                             \
      unsigned ne = ((MEV) >> (ks * 16 + kgrp * 4)) & 0xfu;                      \
      unsigned no = ((MOD) >> (ks * 16 + kgrp * 4)) & 0xfu;                      \
      int jloc = (SBASE) + ks * 32 + kgrp * 8;                                   \
      f32x4 sa = *(const f32x4*)&s2l[jloc];                                      \
      f32x4 sb = *(const f32x4*)&s2l[jloc + 4];                                  \
      f16x8 af;                                                                  \
      af[0] = wel(ne & 1u, sa[0], s10, m0, sum0);                                \
      af[1] = wel(no & 1u, sa[1], s10, m0, sum0);                                \
      af[2] = wel(ne & 2u, sa[2], s10, m0, sum0);                                \
      af[3] = wel(no & 2u, sa[3], s10, m0, sum0);                                \
      af[4] = wel(ne & 4u, sb[0], s10, m0, sum0);                                \
      af[5] = wel(no & 4u, sb[1], s10, m0, sum0);                                \
      af[6] = wel(ne & 8u, sb[2], s10, m0, sum0);                                \
      af[7] = wel(no & 8u, sb[3], s10, m0, sum0);                                \
      _Pragma("unroll")                                                          \
      for (int cf = 0; cf < 8; ++cf) {                                           \
        f16x8 bfr = *(const f16x8*)&tile[BUFI][(cf * 16 + l15) * 64 +            \
                       ((ks * 32 + kgrp * 8) ^ (l7 * 8))];                       \
        acc[cf] = __builtin_amdgcn_mfma_f32_16x16x32_f16(af, bfr, acc[cf], 0, 0, 0); \
      }                                                                          \
    }                                                                            \
  }

// ---------------- K4: fused attention x h, deep-pipelined superbodies ---------
// grid (SPLITK=8 splits, 128 row-blocks), 256 threads = 4 waves x 16 rows.
// Superbody = 128 j. A/B/C schedule, NO vmcnt(0) in the loop:
//  A: stage tile1[4] + adj(sb+1)[16]; vmcnt(20) retires ONLY prev stage0; barrier.
//  B: compute even (tile0); vmcnt(16) retires stage1, adj stays; barrier.
//  C: stage tile0(sb+1)[4]; compute odd (tile1); vmcnt(4) retires adj after
//     2 bodies of cover (stage0 stays in flight); barrier; ballot next masks.
__global__ void __launch_bounds__(256, 4) k4_main(
    const int* __restrict__ adj, const float* __restrict__ s1g,
    const float* __restrict__ s2g, const unsigned* __restrict__ enc,
    const _Float16* __restrict__ hT,
    float* __restrict__ num_p, float* __restrict__ den_p) {
  __shared__ _Float16 tile[2][128 * 64];
  __shared__ float s2l[JCH];
  int t = threadIdx.x;
  int l = t & 63, wv = t >> 6;
  int l15 = l & 15, kgrp = l >> 4;
  int l7 = l15 & 7;
  int split = blockIdx.x;
  int r0 = blockIdx.y * 64;
  int jbeg = split * JCH;
  int row = r0 + wv * 16 + l15;

  float c2 = dec_f32(*enc);
  float s10 = s1g[row];
  float m0 = s10 + c2; m0 = fmaxf(m0, 0.01f * m0);

  f32x4 acc[8];
#pragma unroll
  for (int cf = 0; cf < 8; ++cf) acc[cf] = (f32x4){0.f, 0.f, 0.f, 0.f};
  float sum0 = 0.f;
  // wave's adj rows base; lane l covers cols (J + 2l, J + 2l + 1) as int2
  const int* abase = adj + (size_t)(r0 + wv * 16) * NN + 2 * l;

  auto stage = [&](int b, int jg) {
    const _Float16* g0 = hT + (size_t)(wv * 32 + (l >> 3)) * NN + jg +
                         (((l & 7) ^ (l >> 3)) * 8);
    _Float16* base = &tile[b][(wv * 32) * 64];
    gl_lds16(g0, base);
    gl_lds16(g0 + (size_t)8 * NN, base + 8 * 64);
    gl_lds16(g0 + (size_t)16 * NN, base + 16 * 64);
    gl_lds16(g0 + (size_t)24 * NN, base + 24 * 64);
  };

  int2 S[16];
#define LOADSET2(J)                                                              \
  _Pragma("unroll")                                                              \
  for (int rr = 0; rr < 16; ++rr)                                                \
    S[rr] = *(const int2*)(abase + (size_t)rr * NN + (J));

  unsigned mev_lo, mev_hi, mod_lo, mod_hi;
#define BALLOTROUTE()                                                            \
  {                                                                              \
    mev_lo = 0u; mev_hi = 0u; mod_lo = 0u; mod_hi = 0u;                          \
    _Pragma("unroll")                                                            \
    for (int rr = 0; rr < 16; ++rr) {                                            \
      unsigned long long be = __ballot(S[rr].x > 0);                             \
      unsigned long long bo = __ballot(S[rr].y > 0);                             \
      bool sel = (l15 == rr);                                                    \
      mev_lo = sel ? (unsigned)be : mev_lo;                                      \
      mev_hi = sel ? (unsigned)(be >> 32) : mev_hi;                              \
      mod_lo = sel ? (unsigned)bo : mod_lo;                                      \
      mod_hi = sel ? (unsigned)(bo >> 32) : mod_hi;                              \
    }                                                                            \
  }

  // ---- prologue: stage tile0(sb0), adj(sb0), s2 slice; full drain; ballot ----
  stage(0, jbeg);
  LOADSET2(jbeg)
  *(float4*)&s2l[t * 4] = *(const float4*)(s2g + jbeg + t * 4);
  asm volatile("s_waitcnt vmcnt(0) lgkmcnt(0)" ::: "memory");
  __builtin_amdgcn_s_barrier();
  __builtin_amdgcn_sched_barrier(0);
  BALLOTROUTE()

#pragma unroll 1
  for (int sb = 0; sb < NSB; ++sb) {
    int sjb = jbeg + sb * 128;   // superbody global j base
    int sbase = sb * 128;        // superbody s2l base
    bool nxt = (sb + 1 < NSB);
    // ---- A: issue stage(tile1) + adj(sb+1); retire prev stage0 only ----
    stage(1, sjb + 64);
    if (nxt) { LOADSET2(sjb + 128) }
    __builtin_amdgcn_sched_barrier(0);
    if (nxt) asm volatile("s_waitcnt vmcnt(20)" ::: "memory");  // -> retires prev stage0
    else     asm volatile("s_waitcnt vmcnt(4)" ::: "memory");   // tail: only stage1 left behind
    __builtin_amdgcn_s_barrier();   // tile0 ready
    __builtin_amdgcn_sched_barrier(0);
    // ---- B: even body (tile0) ----
    K4COMPUTE(mev_lo, mod_lo, 0, sbase)
    __builtin_amdgcn_sched_barrier(0);
    if (nxt) asm volatile("s_waitcnt vmcnt(16)" ::: "memory");  // retires stage1, adj in flight
    else     asm volatile("s_waitcnt vmcnt(0)" ::: "memory");
    __builtin_amdgcn_s_barrier();   // tile1 ready
    __builtin_amdgcn_sched_barrier(0);
    // ---- C: stage tile0(sb+1); odd body (tile1); retire adj; ballot ----
    if (nxt) stage(0, sjb + 128);
    __builtin_amdgcn_sched_barrier(0);
    K4COMPUTE(mev_hi, mod_hi, 1, sbase + 64)
    __builtin_amdgcn_sched_barrier(0);
    if (nxt) {
      asm volatile("s_waitcnt vmcnt(4)" ::: "memory");  // retires adj set (2-body cover)
      __builtin_amdgcn_s_barrier();   // WAR: tile1 reads done before next A stages it
      __builtin_amdgcn_sched_barrier(0);
      BALLOTROUTE()
    }
  }

  // row sums: lanes kgrp 0..3 of same l15 combine
  sum0 += __shfl_xor(sum0, 16);
  sum0 += __shfl_xor(sum0, 32);
  size_t sbase2 = (size_t)split * NN;
  if (l < 16) den_p[sbase2 + r0 + wv * 16 + l] = sum0;
  // C/D layout: col = l&15, row = kgrp*4 + i
#pragma unroll
  for (int cf = 0; cf < 8; ++cf) {
#pragma unroll
    for (int i = 0; i < 4; ++i) {
      int orow = r0 + wv * 16 + kgrp * 4 + i;
      int ocol = cf * 16 + l15;
      num_p[(sbase2 + orow) * (size_t)FO + ocol] = acc[cf][i];
    }
  }
}

// ---------------- K5: finalize out = elu(sum(num)/sum(den)) ----------------
__global__ void k5_fin(const float* __restrict__ num_p, const float* __restrict__ den_p,
                       float* __restrict__ out) {
  int idx = blockIdx.x * 256 + threadIdx.x;
  int row = idx >> 7;
  float num = 0.f, den = 0.f;
#pragma unroll
  for (int s = 0; s < SPLITK; ++s) {
    num += num_p[(size_t)s * (NN * FO) + idx];
    den += den_p[(size_t)s * NN + row];
  }
  float v = num / den;
  out[idx] = v > 0.f ? v : expm1f(v);
}

extern "C" void kernel_launch(void* const* d_in, const int* in_sizes, int n_in,
                              void* d_out, int out_size, void* d_ws, size_t ws_size,
                              hipStream_t stream) {
  const float* x   = (const float*)d_in[0];
  const int*   adj = (const int*)d_in[1];
  const float* W   = (const float*)d_in[2];
  const float* a   = (const float*)d_in[3];
  float* out = (float*)d_out;
  char* ws = (char*)d_ws;

  float*     h     = (float*)ws;                                   // 4 MB
  _Float16*  hT    = (_Float16*)(ws + ((size_t)4 << 20));          // 2 MB
  float*     s1    = (float*)(ws + ((size_t)6 << 20));             // 32 KB
  float*     s2    = (float*)(ws + ((size_t)6 << 20) + (32u << 10));
  unsigned*  enc   = (unsigned*)(ws + ((size_t)6 << 20) + (64u << 10));
  float*     den_p = (float*)(ws + ((size_t)6 << 20) + (128u << 10)); // 256 KB
  float*     num_p = (float*)(ws + ((size_t)7 << 20));             // 8 * 4 MB

  k1_xw<<<dim3(256), dim3(256), 0, stream>>>(x, W, h, enc);
  k2_prep<<<dim3(128), dim3(256), 0, stream>>>(h, a, hT, s1, s2, enc);
  k4_main<<<dim3(SPLITK, 128), dim3(256), 0, stream>>>(adj, s1, s2, enc, hT,
                                                       num_p, den_p);
  k5_fin<<<dim3((NN * FO) / 256), dim3(256), 0, stream>>>(num_p, den_p, out);
}

// Round 11
// 117.997 us; speedup vs baseline: 1.4539x; 1.0127x over previous
//
#include <hip/hip_runtime.h>
#include <hip/hip_bf16.h>
#include <cstdint>
#include <cstddef>

#define NN 8192
#define FIN 256
#define FO 128
#define SPLITK 8
#define JCH 1024     // NN / SPLITK
#define TILE_E (128 * 64)

typedef float f32x4 __attribute__((ext_vector_type(4)));
typedef _Float16 f16x8 __attribute__((ext_vector_type(8)));
typedef unsigned long long ull;

typedef __attribute__((address_space(3))) void lds_void;
typedef const __attribute__((address_space(1))) void glb_void;
__device__ __forceinline__ void gl_lds16(const void* g, void* l) {
  __builtin_amdgcn_global_load_lds((glb_void*)g, (lds_void*)l, 16, 0, 0);
}

__device__ __forceinline__ unsigned enc_f32(float f) {
  unsigned u = __float_as_uint(f);
  return (u & 0x80000000u) ? ~u : (u | 0x80000000u);
}
__device__ __forceinline__ float dec_f32(unsigned u) {
  unsigned b = (u & 0x80000000u) ? (u ^ 0x80000000u) : ~u;
  return __uint_as_float(b);
}

// ---------------- K1: h = x @ W  (8192x256 @ 256x128) ----------------
__global__ void k1_xw(const float* __restrict__ x, const float* __restrict__ W,
                      float* __restrict__ h, unsigned* __restrict__ enc) {
  __shared__ float xs[32 * 66];
  __shared__ float Ws[64 * 128];
  int t = threadIdx.x;
  int r0 = blockIdx.x * 32;
  if (blockIdx.x == 0 && t == 0) *enc = 0u;  // init for K2's atomicMax
  int r = t & 31, cg = t >> 5;
  float acc[16];
#pragma unroll
  for (int i = 0; i < 16; ++i) acc[i] = 0.f;
  for (int ko = 0; ko < 4; ++ko) {
    __syncthreads();
    {
      int rr = t >> 3, kc = (t & 7) * 8;
      const float2* src = (const float2*)(x + (size_t)(r0 + rr) * FIN + ko * 64 + kc);
      float2* dst = (float2*)&xs[rr * 66 + kc];
#pragma unroll
      for (int q = 0; q < 4; ++q) dst[q] = src[q];
    }
    {
      int kk = t >> 2, q = t & 3;
      const float4* src = (const float4*)(W + (size_t)(ko * 64 + kk) * FO + q * 32);
      float4* dst = (float4*)&Ws[kk * 128 + q * 32];
#pragma unroll
      for (int i = 0; i < 8; ++i) dst[i] = src[i];
    }
    __syncthreads();
#pragma unroll 8
    for (int kk = 0; kk < 64; ++kk) {
      float xv = xs[r * 66 + kk];
      const float4* wr = (const float4*)&Ws[kk * 128 + cg * 16];
      float4 w0 = wr[0], w1 = wr[1], w2 = wr[2], w3 = wr[3];
      acc[0]  = fmaf(xv, w0.x, acc[0]);  acc[1]  = fmaf(xv, w0.y, acc[1]);
      acc[2]  = fmaf(xv, w0.z, acc[2]);  acc[3]  = fmaf(xv, w0.w, acc[3]);
      acc[4]  = fmaf(xv, w1.x, acc[4]);  acc[5]  = fmaf(xv, w1.y, acc[5]);
      acc[6]  = fmaf(xv, w1.z, acc[6]);  acc[7]  = fmaf(xv, w1.w, acc[7]);
      acc[8]  = fmaf(xv, w2.x, acc[8]);  acc[9]  = fmaf(xv, w2.y, acc[9]);
      acc[10] = fmaf(xv, w2.z, acc[10]); acc[11] = fmaf(xv, w2.w, acc[11]);
      acc[12] = fmaf(xv, w3.x, acc[12]); acc[13] = fmaf(xv, w3.y, acc[13]);
      acc[14] = fmaf(xv, w3.z, acc[14]); acc[15] = fmaf(xv, w3.w, acc[15]);
    }
  }
  float* hp = h + (size_t)(r0 + r) * FO + cg * 16;
#pragma unroll
  for (int i = 0; i < 4; ++i)
    ((float4*)hp)[i] = make_float4(acc[4 * i], acc[4 * i + 1], acc[4 * i + 2], acc[4 * i + 3]);
}

// ---------------- K2: hT (fp16 transpose), s1, s2, max(s2) ----------------
__global__ void k2_prep(const float* __restrict__ h, const float* __restrict__ a,
                        _Float16* __restrict__ hT,
                        float* __restrict__ s1, float* __restrict__ s2,
                        unsigned* __restrict__ enc) {
  __shared__ float ht[64 * 129];
  int t = threadIdx.x;
  int r0 = blockIdx.x * 64;
  {
    int rr = t >> 2, q = t & 3;
    const float4* src = (const float4*)(h + (size_t)(r0 + rr) * FO + q * 32);
    float* dst = &ht[rr * 129 + q * 32];
#pragma unroll
    for (int i = 0; i < 8; ++i) {
      float4 v = src[i];
      dst[4 * i + 0] = v.x; dst[4 * i + 1] = v.y;
      dst[4 * i + 2] = v.z; dst[4 * i + 3] = v.w;
    }
  }
  __syncthreads();
  {
    int c = t >> 1, half = t & 1;
    alignas(16) _Float16 buf[32];
#pragma unroll
    for (int i = 0; i < 32; ++i) buf[i] = (_Float16)ht[(half * 32 + i) * 129 + c];
    int4* d = (int4*)(hT + (size_t)c * NN + r0 + half * 32);
#pragma unroll
    for (int i = 0; i < 4; ++i) d[i] = ((const int4*)buf)[i];
  }
  if (t < 64) {
    int row = r0 + t;
    float v1 = 0.f, v2 = 0.f;
#pragma unroll 16
    for (int c = 0; c < FO; ++c) {
      float hv = ht[t * 129 + c];
      v1 = fmaf(hv, a[c], v1);
      v2 = fmaf(hv, a[FO + c], v2);
    }
    s1[row] = v1; s2[row] = v2;
    float m = v2;
#pragma unroll
    for (int off = 1; off < 64; off <<= 1) m = fmaxf(m, __shfl_xor(m, off));
    if (t == 0) atomicMax(enc, enc_f32(m));
  }
}

// weight: w = bit ? exp(leaky(s1+s2) - m) : 0, rounded to fp16;
// den accumulates the *rounded* weight in f32 for exact normalization consistency.
__device__ __forceinline__ _Float16 wel(unsigned av, float s2v, float s1v, float mv, float& sum) {
  float tt = s1v + s2v;
  tt = fmaxf(tt, 0.01f * tt);  // leaky_relu
  float wf = av ? __expf(tt - mv) : 0.f;
  _Float16 wh = (_Float16)wf;
  sum += (float)wh;
  return wh;
}

// Load one 16-row adj window: lane l -> cols (J + 4l .. 4l+3), ONE dwordx4 =
// 1 KB contiguous per row per instruction (k0's proven streaming granule).
#define LOADSET4(BASE, J)                                                        \
  _Pragma("unroll")                                                              \
  for (int rr = 0; rr < 16; ++rr)                                                \
    S[rr] = *(const int4*)((BASE) + (size_t)rr * NN + (J) + 4 * l);

// Ballot S (16 rows x 4 col-classes) -> per-lane mask words for row l15,
// pre-shifted by kgrp*2. Word w bit b (after shift) = col 4*(b+kgrp/2...)
// i.e. col c: word = c&3, bit = c>>2.
#define ROUTE4(W0, W1, W2, W3)                                                   \
  {                                                                              \
    ull a0 = 0, a1 = 0, a2 = 0, a3 = 0;                                          \
    _Pragma("unroll")                                                            \
    for (int rr = 0; rr < 16; ++rr) {                                            \
      ull bx = __ballot(S[rr].x > 0);                                            \
      ull by = __ballot(S[rr].y > 0);                                            \
      ull bz = __ballot(S[rr].z > 0);                                            \
      ull bw = __ballot(S[rr].w > 0);                                            \
      bool sel = (l15 == rr);                                                    \
      a0 = sel ? bx : a0; a1 = sel ? by : a1;                                    \
      a2 = sel ? bz : a2; a3 = sel ? bw : a3;                                    \
    }                                                                            \
    W0 = a0 >> sh2; W1 = a1 >> sh2; W2 = a2 >> sh2; W3 = a3 >> sh2;              \
  }

// A-fragment for one row-group: af[e] <-> col = body*64 + ks*32 + kgrp*8 + e.
// bit = (word e&3) >> (P*16 + ks*8 + (e>>2))  [masks pre-shifted by kgrp*2].
#define AFRAG(AF, W0, W1, W2, W3, SH, SA4, SB4, S1V, MV, SUM)                    \
  {                                                                              \
    unsigned b0 = (unsigned)((W0) >> (SH));                                      \
    unsigned b1 = (unsigned)((W1) >> (SH));                                      \
    unsigned b2 = (unsigned)((W2) >> (SH));                                      \
    unsigned b3 = (unsigned)((W3) >> (SH));                                      \
    AF[0] = wel(b0 & 1u, SA4[0], S1V, MV, SUM);                                  \
    AF[1] = wel(b1 & 1u, SA4[1], S1V, MV, SUM);                                  \
    AF[2] = wel(b2 & 1u, SA4[2], S1V, MV, SUM);                                  \
    AF[3] = wel(b3 & 1u, SA4[3], S1V, MV, SUM);                                  \
    AF[4] = wel(b0 & 2u, SB4[0], S1V, MV, SUM);                                  \
    AF[5] = wel(b1 & 2u, SB4[1], S1V, MV, SUM);                                  \
    AF[6] = wel(b2 & 2u, SB4[2], S1V, MV, SUM);                                  \
    AF[7] = wel(b3 & 2u, SB4[3], S1V, MV, SUM);                                  \
  }

// One body (64 j): both row-groups share each B-fragment read (2 MFMA per read).
#define BODYCOMP(P, T)                                                           \
  {                                                                              \
    const _Float16* tb = tbase + ((T) % 3) * TILE_E;                             \
    _Pragma("unroll")                                                            \
    for (int ks = 0; ks < 2; ++ks) {                                             \
      int jloc = (T) * 64 + ks * 32 + kgrp * 8;                                  \
      f32x4 sa = *(const f32x4*)&s2l[jloc];                                      \
      f32x4 sb = *(const f32x4*)&s2l[jloc + 4];                                  \
      f16x8 afA, afB;                                                            \
      AFRAG(afA, mA0, mA1, mA2, mA3, (P) * 16 + ks * 8, sa, sb, s1A, mvA, sumA)  \
      AFRAG(afB, mBc0, mBc1, mBc2, mBc3, (P) * 16 + ks * 8, sa, sb, s1B, mvB, sumB) \
      _Pragma("unroll")                                                          \
      for (int cf = 0; cf < 8; ++cf) {                                           \
        f16x8 bfr = *(const f16x8*)&tb[(cf * 16 + l15) * 64 +                    \
                       ((ks * 32 + kgrp * 8) ^ (l7 * 8))];                       \
        accA[cf] = __builtin_amdgcn_mfma_f32_16x16x32_f16(afA, bfr, accA[cf], 0, 0, 0); \
        accB[cf] = __builtin_amdgcn_mfma_f32_16x16x32_f16(afB, bfr, accB[cf], 0, 0, 0); \
      }                                                                          \
    }                                                                            \
  }

#define ENDBODY(VM)                                                              \
  __builtin_amdgcn_sched_barrier(0);                                             \
  asm volatile("s_waitcnt vmcnt(" #VM ")" ::: "memory");                         \
  __builtin_amdgcn_s_barrier();                                                  \
  __builtin_amdgcn_sched_barrier(0);

// ---------------- K4: fused attention x h --------------------------------------
// grid (SPLITK=8, 64), 256 threads = 4 waves x 32 rows (2 row-groups of 16).
// adj: int4 (1 KB/row/instruction) per 256-j window; ONE S[16] array time-shared:
//   body 4k:   route A(window k) from S, then S <- B-rows(window k+1)
//   body 4k+2: route B(window k+1) -> mBn, then S <- A-rows(window k+1)
// (2-body latency cover each; sets never co-resident -> 64 VGPR in flight).
// hT tile [128][64] fp16 x 3 buffers, both-sides XOR swizzle, stage at body t
// targets buffer (t+2)%3. Uniform counted vmcnt(20) per body (never 0 mid-loop).
__global__ void __launch_bounds__(256, 2) k4_main(
    const int* __restrict__ adj, const float* __restrict__ s1g,
    const float* __restrict__ s2g, const unsigned* __restrict__ enc,
    const _Float16* __restrict__ hT,
    float* __restrict__ num_p, float* __restrict__ den_p) {
  __shared__ _Float16 tile[3][TILE_E];
  __shared__ float s2l[JCH];
  int t = threadIdx.x;
  int l = t & 63, wv = t >> 6;
  int l15 = l & 15, kgrp = l >> 4;
  int l7 = l15 & 7;
  int sh2 = kgrp * 2;
  int split = blockIdx.x;
  int r0 = blockIdx.y * 128;
  int jbeg = split * JCH;

  int rowA = r0 + wv * 32 + l15;
  int rowB = rowA + 16;
  float c2 = dec_f32(*enc);
  float s1A = s1g[rowA], s1B = s1g[rowB];
  float mvA = s1A + c2; mvA = fmaxf(mvA, 0.01f * mvA);
  float mvB = s1B + c2; mvB = fmaxf(mvB, 0.01f * mvB);

  f32x4 accA[8], accB[8];
#pragma unroll
  for (int cf = 0; cf < 8; ++cf) {
    accA[cf] = (f32x4){0.f, 0.f, 0.f, 0.f};
    accB[cf] = (f32x4){0.f, 0.f, 0.f, 0.f};
  }
  float sumA = 0.f, sumB = 0.f;
  const int* aA = adj + (size_t)(r0 + wv * 32) * NN;
  const int* aB = aA + (size_t)16 * NN;
  const _Float16* tbase = &tile[0][0];

  // stage one 128x64 tile buffer; wave wv covers tile rows wv*32..+31.
  // linear LDS dest, global col slot pre-XOR'd with row&7 (both-sides swizzle).
  auto stage = [&](int b, int jg) {
    const _Float16* g0 = hT + (size_t)(wv * 32 + (l >> 3)) * NN + jg +
                         (((l & 7) ^ (l >> 3)) * 8);
    _Float16* base = &tile[b][(wv * 32) * 64];
    gl_lds16(g0, base);
    gl_lds16(g0 + (size_t)8 * NN, base + 8 * 64);
    gl_lds16(g0 + (size_t)16 * NN, base + 16 * 64);
    gl_lds16(g0 + (size_t)24 * NN, base + 24 * 64);
  };

  int4 S[16];
  ull mA0, mA1, mA2, mA3;          // group-A masks, current window
  ull mBc0, mBc1, mBc2, mBc3;      // group-B masks, current window
  ull mBn0, mBn1, mBn2, mBn3;      // group-B masks, next window

  // ---- prologue: stage bodies 0,1; route A0 and B0; s2 slice ----
  stage(0, jbeg);
  stage(1, jbeg + 64);
  LOADSET4(aA, jbeg)
  ROUTE4(mA0, mA1, mA2, mA3)        // compiler inserts the S-arrival wait
  LOADSET4(aB, jbeg)
  *(float4*)&s2l[t * 4] = *(const float4*)(s2g + jbeg + t * 4);
  ROUTE4(mBc0, mBc1, mBc2, mBc3)
  asm volatile("s_waitcnt vmcnt(0) lgkmcnt(0)" ::: "memory");
  __builtin_amdgcn_s_barrier();
  __builtin_amdgcn_sched_barrier(0);

  // ---- main: k = 0..2 (bodies 0..11), then tail k=3 (bodies 12..15) ----
#pragma unroll 1
  for (int k = 0; k < 3; ++k) {
    int t0 = 4 * k;
    // p0: route A(window k) [k>0], S <- B(window k+1), promote B masks [k>0]
    stage((t0 + 2) % 3, jbeg + (t0 + 2) * 64);
    if (k) { ROUTE4(mA0, mA1, mA2, mA3) }
    LOADSET4(aB, jbeg + (k + 1) * 256)
    if (k) { mBc0 = mBn0; mBc1 = mBn1; mBc2 = mBn2; mBc3 = mBn3; }
    __builtin_amdgcn_sched_barrier(0);
    BODYCOMP(0, t0)
    ENDBODY(20)
    // p1
    stage((t0 + 3) % 3, jbeg + (t0 + 3) * 64);
    __builtin_amdgcn_sched_barrier(0);
    BODYCOMP(1, t0 + 1)
    ENDBODY(20)
    // p2: route B(window k+1) -> mBn, then S <- A(window k+1)
    stage((t0 + 4) % 3, jbeg + (t0 + 4) * 64);
    ROUTE4(mBn0, mBn1, mBn2, mBn3)
    LOADSET4(aA, jbeg + (k + 1) * 256)
    __builtin_amdgcn_sched_barrier(0);
    BODYCOMP(2, t0 + 2)
    ENDBODY(20)
    // p3
    stage((t0 + 5) % 3, jbeg + (t0 + 5) * 64);
    __builtin_amdgcn_sched_barrier(0);
    BODYCOMP(3, t0 + 3)
    ENDBODY(20)
  }
  // ---- tail k=3: bodies 12..15 (windows exhausted; drain stages) ----
  stage(14 % 3, jbeg + 14 * 64);
  ROUTE4(mA0, mA1, mA2, mA3)                       // A(window 3), loaded at body 10
  mBc0 = mBn0; mBc1 = mBn1; mBc2 = mBn2; mBc3 = mBn3;  // B(window 3), routed at body 10
  __builtin_amdgcn_sched_barrier(0);
  BODYCOMP(0, 12)
  ENDBODY(4)
  stage(15 % 3, jbeg + 15 * 64);
  __builtin_amdgcn_sched_barrier(0);
  BODYCOMP(1, 13)
  ENDBODY(4)
  BODYCOMP(2, 14)
  ENDBODY(0)
  BODYCOMP(3, 15)

  // row sums: lanes kgrp 0..3 of same l15 combine
  sumA += __shfl_xor(sumA, 16); sumA += __shfl_xor(sumA, 32);
  sumB += __shfl_xor(sumB, 16); sumB += __shfl_xor(sumB, 32);
  size_t sb2 = (size_t)split * NN;
  if (l < 16) {
    den_p[sb2 + r0 + wv * 32 + l] = sumA;
    den_p[sb2 + r0 + wv * 32 + 16 + l] = sumB;
  }
  // C/D layout: col = l&15, row = kgrp*4 + i  (per group)
#pragma unroll
  for (int cf = 0; cf < 8; ++cf) {
#pragma unroll
    for (int i = 0; i < 4; ++i) {
      int orow = r0 + wv * 32 + kgrp * 4 + i;
      int ocol = cf * 16 + l15;
      num_p[(sb2 + orow) * (size_t)FO + ocol] = accA[cf][i];
      num_p[(sb2 + orow + 16) * (size_t)FO + ocol] = accB[cf][i];
    }
  }
}

// ---------------- K5: finalize out = elu(sum(num)/sum(den)) ----------------
__global__ void k5_fin(const float* __restrict__ num_p, const float* __restrict__ den_p,
                       float* __restrict__ out) {
  int idx = blockIdx.x * 256 + threadIdx.x;
  int row = idx >> 7;
  float num = 0.f, den = 0.f;
#pragma unroll
  for (int s = 0; s < SPLITK; ++s) {
    num += num_p[(size_t)s * (NN * FO) + idx];
    den += den_p[(size_t)s * NN + row];
  }
  float v = num / den;
  out[idx] = v > 0.f ? v : expm1f(v);
}

extern "C" void kernel_launch(void* const* d_in, const int* in_sizes, int n_in,
                              void* d_out, int out_size, void* d_ws, size_t ws_size,
                              hipStream_t stream) {
  const float* x   = (const float*)d_in[0];
  const int*   adj = (const int*)d_in[1];
  const float* W   = (const float*)d_in[2];
  const float* a   = (const float*)d_in[3];
  float* out = (float*)d_out;
  char* ws = (char*)d_ws;

  float*     h     = (float*)ws;                                   // 4 MB
  _Float16*  hT    = (_Float16*)(ws + ((size_t)4 << 20));          // 2 MB
  float*     s1    = (float*)(ws + ((size_t)6 << 20));             // 32 KB
  float*     s2    = (float*)(ws + ((size_t)6 << 20) + (32u << 10));
  unsigned*  enc   = (unsigned*)(ws + ((size_t)6 << 20) + (64u << 10));
  float*     den_p = (float*)(ws + ((size_t)6 << 20) + (128u << 10)); // 256 KB
  float*     num_p = (float*)(ws + ((size_t)7 << 20));             // 8 * 4 MB

  k1_xw<<<dim3(256), dim3(256), 0, stream>>>(x, W, h, enc);
  k2_prep<<<dim3(128), dim3(256), 0, stream>>>(h, a, hT, s1, s2, enc);
  k4_main<<<dim3(SPLITK, 64), dim3(256), 0, stream>>>(adj, s1, s2, enc, hT,
                                                      num_p, den_p);
  k5_fin<<<dim3((NN * FO) / 256), dim3(256), 0, stream>>>(num_p, den_p, out);
}